// Round 14
// baseline (685.566 us; speedup 1.0000x reference)
//
#include <hip/hip_runtime.h>

// GraphSAGE layer: B=8, N=5000, E=100000, D=128. All float tensors f32; edge_index int32.
// R14 pipeline (3 dispatches): memset(cnt) -> fill (XCD-affine buckets + x->bf16 conv
//   + packW) -> fused (flat-list gather via ds_add_f32 -> MFMA gemm + ReLU+LN+mask).
// R13 post-mortem: gather latency-bound on per-node dependent chains (VALU 33%).
// ds_add_f32 (no return value -> no dep chain) lets waves stride a flat edge list
// with every iteration independent. agg stored de-interleaved (lo ch 0-63, hi 64-127)
// so each lane's 2 adds are 2-way bank aliasing (free, m136).

#define B_ 8
#define N_ 5000
#define E_ 100000
#define D_ 128
#define EPS_ 1e-5f
#define NNODES (B_ * N_)   // 40000
#define NEDGES (B_ * E_)   // 800000
#define JB 313             // 16-node blocks per batch (312*16+8 = 5000)
#define EPB ((E_ + 255) / 256)        // 391 edge-blocks per batch (ceil — R9 lesson)
#define FILL_BLOCKS (8 * EPB)         // 3128
#define CONV_BLOCKS 2500              // x -> bf16: 2048 elems/block
#define CAP 64             // bucket capacity per node (avg deg 20, P(ovf) ~ 5e-14)
#define LDSP 136           // padded bf16 row stride (272 B -> 2-way bank alias, free)

typedef __bf16 bf16x8 __attribute__((ext_vector_type(8)));
typedef float  f32x4  __attribute__((ext_vector_type(4)));

static __device__ __forceinline__ unsigned short f2bf(float f) {
    union { float f; unsigned int i; } c; c.f = f;
    unsigned int i = c.i;
    i += 0x7fffu + ((i >> 16) & 1u);
    return (unsigned short)(i >> 16);
}
static __device__ __forceinline__ float bflo(unsigned int u) {
    return __uint_as_float(u << 16);
}
static __device__ __forceinline__ float bfhi(unsigned int u) {
    return __uint_as_float(u & 0xffff0000u);
}

// ---------- fill: XCD-affine buckets (0..3127) + x->bf16 (3128..5627) + packW ----------
__global__ __launch_bounds__(256) void fill_k(
    const int* __restrict__ ei, const float* __restrict__ em,
    int* __restrict__ cnt, int2* __restrict__ entries,
    const float* __restrict__ x, unsigned short* __restrict__ xbf,
    const float* __restrict__ Wself, const float* __restrict__ Wnb,
    unsigned short* __restrict__ Bt)
{
    int blk = blockIdx.x;
    if (blk < FILL_BLOCKS) {
        int b = blk & 7;                    // batch -> XCD (round-robin dispatch)
        int e = (blk >> 3) * 256 + threadIdx.x;
        if (e >= E_) return;
        const int* eib = ei + (size_t)b * 2 * E_;
        int src = eib[e];
        int tgt = eib[E_ + e];
        float m = em[(size_t)b * E_ + e];
        if (m != 0.0f) {
            int g = b * N_ + tgt;
            int slot = atomicAdd(&cnt[g], 1);
            if (slot < CAP)
                entries[((size_t)g << 6) + slot] =
                    make_int2(b * N_ + src, __float_as_int(m));
        }
    } else if (blk < FILL_BLOCKS + CONV_BLOCKS) {
        size_t base = (size_t)(blk - FILL_BLOCKS) * 2048 + threadIdx.x * 8;
        float4 va = *(const float4*)(x + base);
        float4 vb = *(const float4*)(x + base + 4);
        uint4 o;
        o.x = (unsigned int)f2bf(va.x) | ((unsigned int)f2bf(va.y) << 16);
        o.y = (unsigned int)f2bf(va.z) | ((unsigned int)f2bf(va.w) << 16);
        o.z = (unsigned int)f2bf(vb.x) | ((unsigned int)f2bf(vb.y) << 16);
        o.w = (unsigned int)f2bf(vb.z) | ((unsigned int)f2bf(vb.w) << 16);
        *(uint4*)(xbf + base) = o;
    } else {
        int n = blk - FILL_BLOCKS - CONV_BLOCKS;   // 0..127
        int k = threadIdx.x;                       // 0..255
        float v = (k < 128) ? Wself[(size_t)k * D_ + n]
                            : Wnb[(size_t)(k - 128) * D_ + n];
        Bt[(size_t)n * 256 + k] = f2bf(v);
    }
}

// ---------- fused: flat-list LDS-atomic gather + MFMA GEMM + ReLU + LN + mask ----------
// Grid 8*JB; blk&7 = batch (XCD affinity), blk>>3 = 16-node group within batch.
__global__ __launch_bounds__(256) void fused_k(
    const unsigned short* __restrict__ xbf, const int* __restrict__ cnt,
    const int2* __restrict__ entries,
    const unsigned short* __restrict__ Bt,
    const float* __restrict__ bself, const float* __restrict__ bnb,
    const float* __restrict__ gamma, const float* __restrict__ beta,
    const float* __restrict__ nmask, float* __restrict__ out)
{
    __shared__ unsigned short xs[16][LDSP];       // own rows, bf16
    __shared__ unsigned short as[16][LDSP];       // agg rows, bf16 (after A3)
    __shared__ float aggf[16][128];               // f32 accum, DE-INTERLEAVED:
                                                  //   [j][l]    = ch 2l   (lo)
                                                  //   [j][64+l] = ch 2l+1 (hi)
    __shared__ float csumf[16];
    __shared__ int   csh[16];
    __shared__ int   pre[17];
    __shared__ int2  list[16 * CAP];              // flat edge list (8 KB)
    __shared__ float red[4][2][16];

    int t = threadIdx.x;
    int lane = t & 63, wv = t >> 6;
    int b = blockIdx.x & 7;
    int j = blockIdx.x >> 3;               // 0..JB-1
    int i0 = j * 16;
    int g0 = b * N_ + i0;
    int limit = N_ - i0; if (limit > 16) limit = 16;

    // ---- A0: stage xs, zero aggf/csumf, build per-node prefix ----
    #pragma unroll
    for (int lr = wv * 4; lr < wv * 4 + 4; ++lr) {
        unsigned int v = 0;
        if (lr < limit)
            v = ((const unsigned int*)(xbf + (size_t)(g0 + lr) * D_))[lane];
        ((unsigned int*)&xs[lr][0])[lane] = v;
    }
    {
        float* az = &aggf[0][0];
        #pragma unroll
        for (int i = t; i < 16 * 128; i += 256) az[i] = 0.0f;
        if (t < 16) csumf[t] = 0.0f;
    }
    if (t == 0) {
        int r = 0;
        #pragma unroll
        for (int jj = 0; jj < 16; ++jj) {
            int c = (jj < limit) ? cnt[g0 + jj] : 0;
            if (c > CAP) c = CAP;
            csh[jj] = c;
            pre[jj] = r;
            r += c;
        }
        pre[16] = r;
    }
    __syncthreads();

    // ---- A1: compact buckets into flat LDS list ----
    for (int s = t; s < 16 * CAP; s += 256) {
        int jj = s >> 6, k = s & 63;
        if (k < csh[jj]) {
            int2 e = entries[((size_t)(g0 + jj) << 6) + k];
            list[pre[jj] + k] = make_int2((e.x & 0xFFFFF) | (jj << 20), e.y);
        }
    }
    __syncthreads();

    // ---- A2: waves stride the flat list; ds_add_f32 accumulation (no dep chains) ----
    {
        int tot = pre[16];
        for (int i = wv; i < tot; i += 4) {
            int2 e = list[i];                      // LDS broadcast (all lanes same addr)
            int   src = e.x & 0xFFFFF;
            int   jj  = ((unsigned)e.x) >> 20;
            float m   = __int_as_float(e.y);
            unsigned int v = ((const unsigned int*)(xbf + (size_t)src * D_))[lane];
            atomicAdd(&aggf[jj][lane],      bflo(v) * m);   // ds_add_f32, 2-way free
            atomicAdd(&aggf[jj][64 + lane], bfhi(v) * m);
            if (lane == 0) atomicAdd(&csumf[jj], m);
        }
    }
    __syncthreads();

    // ---- A3: scale + convert to bf16 interleaved rows ----
    {
        int jj = t >> 4, c = t & 15;               // 16 threads per row, 8 ch each
        float inv = 1.0f / fmaxf(csumf[jj], 1.0f);
        uint4 o;
        float lo0 = aggf[jj][4 * c + 0] * inv, hi0 = aggf[jj][64 + 4 * c + 0] * inv;
        float lo1 = aggf[jj][4 * c + 1] * inv, hi1 = aggf[jj][64 + 4 * c + 1] * inv;
        float lo2 = aggf[jj][4 * c + 2] * inv, hi2 = aggf[jj][64 + 4 * c + 2] * inv;
        float lo3 = aggf[jj][4 * c + 3] * inv, hi3 = aggf[jj][64 + 4 * c + 3] * inv;
        o.x = (unsigned int)f2bf(lo0) | ((unsigned int)f2bf(hi0) << 16);
        o.y = (unsigned int)f2bf(lo1) | ((unsigned int)f2bf(hi1) << 16);
        o.z = (unsigned int)f2bf(lo2) | ((unsigned int)f2bf(hi2) << 16);
        o.w = (unsigned int)f2bf(lo3) | ((unsigned int)f2bf(hi3) << 16);
        *(uint4*)&as[jj][8 * c] = o;
    }
    __syncthreads();

    // ---- Phase B: MFMA GEMM; wave wv owns col-tiles 2wv, 2wv+1 ----
    int quad = lane >> 4;
    int lcol = lane & 15;

    f32x4 acc[2];
    acc[0] = (f32x4)0.0f;
    acc[1] = (f32x4)0.0f;

    #pragma unroll
    for (int kk = 0; kk < 4; ++kk) {
        int kof = kk * 32 + quad * 8;
        bf16x8 a = *(const bf16x8*)&xs[lcol][kof];
        #pragma unroll
        for (int p = 0; p < 2; ++p) {
            int tt = wv * 2 + p;
            bf16x8 bf = *(const bf16x8*)(Bt + (size_t)(tt * 16 + lcol) * 256 + kof);
            acc[p] = __builtin_amdgcn_mfma_f32_16x16x32_bf16(a, bf, acc[p], 0, 0, 0);
        }
    }
    #pragma unroll
    for (int kk = 0; kk < 4; ++kk) {
        int kof = kk * 32 + quad * 8;
        bf16x8 a = *(const bf16x8*)&as[lcol][kof];
        #pragma unroll
        for (int p = 0; p < 2; ++p) {
            int tt = wv * 2 + p;
            bf16x8 bf = *(const bf16x8*)(Bt + (size_t)(tt * 16 + lcol) * 256 + 128 + kof);
            acc[p] = __builtin_amdgcn_mfma_f32_16x16x32_bf16(a, bf, acc[p], 0, 0, 0);
        }
    }

    // bias + ReLU; per-wave 32-col LN partials
    float h[2][4];
    float s[4] = {0, 0, 0, 0}, q[4] = {0, 0, 0, 0};
    float gam[2], bet[2];
    #pragma unroll
    for (int p = 0; p < 2; ++p) {
        int col = (wv * 2 + p) * 16 + lcol;
        float bs = bself[col] + bnb[col];
        gam[p] = gamma[col];
        bet[p] = beta[col];
        #pragma unroll
        for (int r = 0; r < 4; ++r) {
            float v = fmaxf(acc[p][r] + bs, 0.0f);
            h[p][r] = v;
            s[r] += v;
            q[r] += v * v;
        }
    }
    #pragma unroll
    for (int r = 0; r < 4; ++r) {
        #pragma unroll
        for (int off = 1; off <= 8; off <<= 1) {
            s[r] += __shfl_xor(s[r], off, 64);
            q[r] += __shfl_xor(q[r], off, 64);
        }
    }
    if (lcol == 0) {
        #pragma unroll
        for (int r = 0; r < 4; ++r) {
            red[wv][0][quad * 4 + r] = s[r];
            red[wv][1][quad * 4 + r] = q[r];
        }
    }
    __syncthreads();

    #pragma unroll
    for (int r = 0; r < 4; ++r) {
        int row = quad * 4 + r;
        int irow = i0 + row;
        if (irow >= N_) continue;
        float S = red[0][0][row] + red[1][0][row] + red[2][0][row] + red[3][0][row];
        float Q = red[0][1][row] + red[1][1][row] + red[2][1][row] + red[3][1][row];
        float mu = S * (1.0f / D_);
        float var = Q * (1.0f / D_) - mu * mu;
        float rin = rsqrtf(fmaxf(var, 0.0f) + EPS_);
        int g = b * N_ + irow;
        float mk = nmask[g];
        float* op = out + (size_t)g * D_;
        #pragma unroll
        for (int p = 0; p < 2; ++p) {
            int col = (wv * 2 + p) * 16 + lcol;
            op[col] = ((h[p][r] - mu) * rin * gam[p] + bet[p]) * mk;
        }
    }
}

extern "C" void kernel_launch(void* const* d_in, const int* in_sizes, int n_in,
                              void* d_out, int out_size, void* d_ws, size_t ws_size,
                              hipStream_t stream)
{
    const float* x     = (const float*)d_in[0];
    const int*   ei    = (const int*)d_in[1];
    const float* nmask = (const float*)d_in[2];
    const float* em    = (const float*)d_in[3];
    const float* Wself = (const float*)d_in[4];
    const float* bself = (const float*)d_in[5];
    const float* Wnb   = (const float*)d_in[6];
    const float* bnb   = (const float*)d_in[7];
    const float* gamma = (const float*)d_in[8];
    const float* beta  = (const float*)d_in[9];
    float* out = (float*)d_out;

    // ws: cnt int[40000] | entries int2[40000*64] (20.48 MB) | Bt bf16[128*256]
    //     | xbf bf16[40000*128] (10.24 MB)   -> ~31 MB total
    int* cnt = (int*)d_ws;
    int2* entries = (int2*)(cnt + NNODES);                       // byte 160000, 8-al
    unsigned short* Bt = (unsigned short*)(entries + (size_t)NNODES * CAP);
    unsigned short* xbf = Bt + (size_t)128 * 256;                // 16-aligned

    hipMemsetAsync(cnt, 0, NNODES * sizeof(int), stream);
    fill_k<<<FILL_BLOCKS + CONV_BLOCKS + 128, 256, 0, stream>>>(
        ei, em, cnt, entries, x, xbf, Wself, Wnb, Bt);
    fused_k<<<8 * JB, 256, 0, stream>>>(xbf, cnt, entries, Bt,
                                        bself, bnb, gamma, beta, nmask, out);
}

// Round 15
// 173.108 us; speedup vs baseline: 3.9603x; 3.9603x over previous
//
#include <hip/hip_runtime.h>

// GraphSAGE layer: B=8, N=5000, E=100000, D=128. All float tensors f32; edge_index int32.
// R15 pipeline (3 dispatches): memset(cnt) -> fill (XCD-affine buckets + x->bf16 conv
//   + packW) -> fused (pair-interleaved bf16 gather -> MFMA gemm + ReLU+LN+mask).
// R14 post-mortem: atomicAdd(__shared__ float) lowers to a ds_cmpst CAS retry loop
// (VALU 4%, lgkmcnt-serialized) -> 10x regression. Reverted to R13 structure.
// R15 change: gather processes 2 nodes per wave simultaneously -> 8 independent
// uint4 loads in flight per 16-lane group (was 4); bounds checks uniform per group.

#define B_ 8
#define N_ 5000
#define E_ 100000
#define D_ 128
#define EPS_ 1e-5f
#define NNODES (B_ * N_)   // 40000
#define NEDGES (B_ * E_)   // 800000
#define JB 313             // 16-node blocks per batch (312*16+8 = 5000)
#define EPB ((E_ + 255) / 256)        // 391 edge-blocks per batch (ceil — R9 lesson)
#define FILL_BLOCKS (8 * EPB)         // 3128
#define CONV_BLOCKS 2500              // x -> bf16: 2048 elems/block
#define CAP 64             // bucket capacity per node (avg deg 20, P(ovf) ~ 5e-14)
#define LDSP 136           // padded bf16 row stride (272 B -> 2-way bank alias, free)

typedef __bf16 bf16x8 __attribute__((ext_vector_type(8)));
typedef float  f32x4  __attribute__((ext_vector_type(4)));

static __device__ __forceinline__ unsigned short f2bf(float f) {
    union { float f; unsigned int i; } c; c.f = f;
    unsigned int i = c.i;
    i += 0x7fffu + ((i >> 16) & 1u);
    return (unsigned short)(i >> 16);
}
static __device__ __forceinline__ float bflo(unsigned int u) {
    return __uint_as_float(u << 16);
}
static __device__ __forceinline__ float bfhi(unsigned int u) {
    return __uint_as_float(u & 0xffff0000u);
}

// ---------- fill: XCD-affine buckets (0..3127) + x->bf16 (3128..5627) + packW ----------
__global__ __launch_bounds__(256) void fill_k(
    const int* __restrict__ ei, const float* __restrict__ em,
    int* __restrict__ cnt, int2* __restrict__ entries,
    const float* __restrict__ x, unsigned short* __restrict__ xbf,
    const float* __restrict__ Wself, const float* __restrict__ Wnb,
    unsigned short* __restrict__ Bt)
{
    int blk = blockIdx.x;
    if (blk < FILL_BLOCKS) {
        int b = blk & 7;                    // batch -> XCD (round-robin dispatch)
        int e = (blk >> 3) * 256 + threadIdx.x;
        if (e >= E_) return;
        const int* eib = ei + (size_t)b * 2 * E_;
        int src = eib[e];
        int tgt = eib[E_ + e];
        float m = em[(size_t)b * E_ + e];
        if (m != 0.0f) {
            int g = b * N_ + tgt;
            int slot = atomicAdd(&cnt[g], 1);
            if (slot < CAP)
                entries[((size_t)g << 6) + slot] =
                    make_int2(b * N_ + src, __float_as_int(m));
        }
    } else if (blk < FILL_BLOCKS + CONV_BLOCKS) {
        size_t base = (size_t)(blk - FILL_BLOCKS) * 2048 + threadIdx.x * 8;
        float4 va = *(const float4*)(x + base);
        float4 vb = *(const float4*)(x + base + 4);
        uint4 o;
        o.x = (unsigned int)f2bf(va.x) | ((unsigned int)f2bf(va.y) << 16);
        o.y = (unsigned int)f2bf(va.z) | ((unsigned int)f2bf(va.w) << 16);
        o.z = (unsigned int)f2bf(vb.x) | ((unsigned int)f2bf(vb.y) << 16);
        o.w = (unsigned int)f2bf(vb.z) | ((unsigned int)f2bf(vb.w) << 16);
        *(uint4*)(xbf + base) = o;
    } else {
        int n = blk - FILL_BLOCKS - CONV_BLOCKS;   // 0..127
        int k = threadIdx.x;                       // 0..255
        float v = (k < 128) ? Wself[(size_t)k * D_ + n]
                            : Wnb[(size_t)(k - 128) * D_ + n];
        Bt[(size_t)n * 256 + k] = f2bf(v);
    }
}

// ---------- gather v5: TWO nodes per wave, 8 loads in flight per 16-lane group ----------
static __device__ __forceinline__ void gather_pair_lds(
    int gA, int gB, bool vA, bool vB, int lane,
    const unsigned short* __restrict__ xbf, const int* __restrict__ cnt,
    const int2* __restrict__ entries,
    unsigned short* dstA, unsigned short* dstB)
{
    int dgA = 0, dgB = 0;
    if (vA) { dgA = cnt[gA]; if (dgA > CAP) dgA = CAP; }
    if (vB) { dgB = cnt[gB]; if (dgB > CAP) dgB = CAP; }
    const int2* epA = entries + ((size_t)gA << 6);
    const int2* epB = entries + ((size_t)gB << 6);
    int grp = lane >> 4;                   // 0..3: which edge of each quad
    int c8 = lane & 15;                    // 16B chunk (8 bf16) within the 256B row

    float aA[8], aB[8];
    #pragma unroll
    for (int i = 0; i < 8; ++i) { aA[i] = 0.f; aB[i] = 0.f; }
    float csA = 0.f, csB = 0.f;

    int2 eeA = (lane < 16 && lane < dgA) ? epA[lane] : make_int2(0, 0);
    int2 eeB = (lane < 16 && lane < dgB) ? epB[lane] : make_int2(0, 0);
    int dgM = dgA > dgB ? dgA : dgB;

    for (int k = 0; k < dgM; k += 16) {
        int2 enA = (lane < 16 && k + 16 + lane < dgA) ? epA[k + 16 + lane]
                                                      : make_int2(0, 0);
        int2 enB = (lane < 16 && k + 16 + lane < dgB) ? epB[k + 16 + lane]
                                                      : make_int2(0, 0);
        #pragma unroll
        for (int j = 0; j < 4; ++j) {
            int eidx = 4 * j + grp;        // uniform within each 16-lane group
            int   sA = __shfl(eeA.x, eidx, 64);
            float mA = __int_as_float(__shfl(eeA.y, eidx, 64));
            int   sB = __shfl(eeB.x, eidx, 64);
            float mB = __int_as_float(__shfl(eeB.y, eidx, 64));
            if (k + eidx < dgA) {
                uint4 v = *(const uint4*)(xbf + (size_t)sA * D_ + 8 * c8);
                aA[0] += bflo(v.x) * mA; aA[1] += bfhi(v.x) * mA;
                aA[2] += bflo(v.y) * mA; aA[3] += bfhi(v.y) * mA;
                aA[4] += bflo(v.z) * mA; aA[5] += bfhi(v.z) * mA;
                aA[6] += bflo(v.w) * mA; aA[7] += bfhi(v.w) * mA;
                csA += mA;
            }
            if (k + eidx < dgB) {
                uint4 v = *(const uint4*)(xbf + (size_t)sB * D_ + 8 * c8);
                aB[0] += bflo(v.x) * mB; aB[1] += bfhi(v.x) * mB;
                aB[2] += bflo(v.y) * mB; aB[3] += bfhi(v.y) * mB;
                aB[4] += bflo(v.z) * mB; aB[5] += bfhi(v.z) * mB;
                aB[6] += bflo(v.w) * mB; aB[7] += bfhi(v.w) * mB;
                csB += mB;
            }
        }
        eeA = enA; eeB = enB;
    }

    // fold the 4 groups (lanes differing in bits 4,5); results valid in all lanes
    #pragma unroll
    for (int i = 0; i < 8; ++i) {
        aA[i] += __shfl_xor(aA[i], 16, 64);
        aA[i] += __shfl_xor(aA[i], 32, 64);
        aB[i] += __shfl_xor(aB[i], 16, 64);
        aB[i] += __shfl_xor(aB[i], 32, 64);
    }
    csA += __shfl_xor(csA, 16, 64); csA += __shfl_xor(csA, 32, 64);
    csB += __shfl_xor(csB, 16, 64); csB += __shfl_xor(csB, 32, 64);

    if (lane < 16) {
        float inv = 1.0f / fmaxf(csA, 1.0f);
        uint4 o;
        o.x = (unsigned int)f2bf(aA[0] * inv) | ((unsigned int)f2bf(aA[1] * inv) << 16);
        o.y = (unsigned int)f2bf(aA[2] * inv) | ((unsigned int)f2bf(aA[3] * inv) << 16);
        o.z = (unsigned int)f2bf(aA[4] * inv) | ((unsigned int)f2bf(aA[5] * inv) << 16);
        o.w = (unsigned int)f2bf(aA[6] * inv) | ((unsigned int)f2bf(aA[7] * inv) << 16);
        *(uint4*)(dstA + 8 * c8) = o;
    } else if (lane < 32) {
        float inv = 1.0f / fmaxf(csB, 1.0f);
        uint4 o;
        o.x = (unsigned int)f2bf(aB[0] * inv) | ((unsigned int)f2bf(aB[1] * inv) << 16);
        o.y = (unsigned int)f2bf(aB[2] * inv) | ((unsigned int)f2bf(aB[3] * inv) << 16);
        o.z = (unsigned int)f2bf(aB[4] * inv) | ((unsigned int)f2bf(aB[5] * inv) << 16);
        o.w = (unsigned int)f2bf(aB[6] * inv) | ((unsigned int)f2bf(aB[7] * inv) << 16);
        *(uint4*)(dstB + 8 * c8) = o;
    }
}

// ---------- fused gather + MFMA GEMM + ReLU + LN + mask ----------
// Grid 8*JB; blk&7 = batch (XCD affinity), blk>>3 = 16-node group within batch.
__global__ __launch_bounds__(256) void fused_k(
    const unsigned short* __restrict__ xbf, const int* __restrict__ cnt,
    const int2* __restrict__ entries,
    const unsigned short* __restrict__ Bt,
    const float* __restrict__ bself, const float* __restrict__ bnb,
    const float* __restrict__ gamma, const float* __restrict__ beta,
    const float* __restrict__ nmask, float* __restrict__ out)
{
    __shared__ unsigned short xs[16][LDSP];
    __shared__ unsigned short as[16][LDSP];
    __shared__ float red[4][2][16];

    int t = threadIdx.x;
    int lane = t & 63, wv = t >> 6;
    int b = blockIdx.x & 7;
    int j = blockIdx.x >> 3;               // 0..JB-1
    int i0 = j * 16;
    int g0 = b * N_ + i0;
    int limit = N_ - i0; if (limit > 16) limit = 16;

    // Phase A: stage own xbf rows + paired gather into LDS (4 rows/wave, 2 pairs).
    #pragma unroll
    for (int lr = wv * 4; lr < wv * 4 + 4; ++lr) {
        unsigned int v = 0;
        if (lr < limit)
            v = ((const unsigned int*)(xbf + (size_t)(g0 + lr) * D_))[lane];
        ((unsigned int*)&xs[lr][0])[lane] = v;
    }
    #pragma unroll
    for (int s = 0; s < 2; ++s) {
        int lrA = wv * 4 + 2 * s;
        int lrB = lrA + 1;
        gather_pair_lds(g0 + lrA, g0 + lrB, lrA < limit, lrB < limit, lane,
                        xbf, cnt, entries, &as[lrA][0], &as[lrB][0]);
    }
    __syncthreads();

    // Phase B: wave wv owns col-tiles 2wv, 2wv+1.
    int quad = lane >> 4;
    int lcol = lane & 15;

    f32x4 acc[2];
    acc[0] = (f32x4)0.0f;
    acc[1] = (f32x4)0.0f;

    #pragma unroll
    for (int kk = 0; kk < 4; ++kk) {
        int kof = kk * 32 + quad * 8;
        bf16x8 a = *(const bf16x8*)&xs[lcol][kof];
        #pragma unroll
        for (int p = 0; p < 2; ++p) {
            int tt = wv * 2 + p;
            bf16x8 bf = *(const bf16x8*)(Bt + (size_t)(tt * 16 + lcol) * 256 + kof);
            acc[p] = __builtin_amdgcn_mfma_f32_16x16x32_bf16(a, bf, acc[p], 0, 0, 0);
        }
    }
    #pragma unroll
    for (int kk = 0; kk < 4; ++kk) {
        int kof = kk * 32 + quad * 8;
        bf16x8 a = *(const bf16x8*)&as[lcol][kof];
        #pragma unroll
        for (int p = 0; p < 2; ++p) {
            int tt = wv * 2 + p;
            bf16x8 bf = *(const bf16x8*)(Bt + (size_t)(tt * 16 + lcol) * 256 + 128 + kof);
            acc[p] = __builtin_amdgcn_mfma_f32_16x16x32_bf16(a, bf, acc[p], 0, 0, 0);
        }
    }

    // bias + ReLU; per-wave 32-col LN partials
    float h[2][4];
    float s[4] = {0, 0, 0, 0}, q[4] = {0, 0, 0, 0};
    float gam[2], bet[2];
    #pragma unroll
    for (int p = 0; p < 2; ++p) {
        int col = (wv * 2 + p) * 16 + lcol;
        float bs = bself[col] + bnb[col];
        gam[p] = gamma[col];
        bet[p] = beta[col];
        #pragma unroll
        for (int r = 0; r < 4; ++r) {
            float v = fmaxf(acc[p][r] + bs, 0.0f);
            h[p][r] = v;
            s[r] += v;
            q[r] += v * v;
        }
    }
    #pragma unroll
    for (int r = 0; r < 4; ++r) {
        #pragma unroll
        for (int off = 1; off <= 8; off <<= 1) {
            s[r] += __shfl_xor(s[r], off, 64);
            q[r] += __shfl_xor(q[r], off, 64);
        }
    }
    if (lcol == 0) {
        #pragma unroll
        for (int r = 0; r < 4; ++r) {
            red[wv][0][quad * 4 + r] = s[r];
            red[wv][1][quad * 4 + r] = q[r];
        }
    }
    __syncthreads();

    #pragma unroll
    for (int r = 0; r < 4; ++r) {
        int row = quad * 4 + r;
        int irow = i0 + row;
        if (irow >= N_) continue;
        float S = red[0][0][row] + red[1][0][row] + red[2][0][row] + red[3][0][row];
        float Q = red[0][1][row] + red[1][1][row] + red[2][1][row] + red[3][1][row];
        float mu = S * (1.0f / D_);
        float var = Q * (1.0f / D_) - mu * mu;
        float rin = rsqrtf(fmaxf(var, 0.0f) + EPS_);
        int g = b * N_ + irow;
        float mk = nmask[g];
        float* op = out + (size_t)g * D_;
        #pragma unroll
        for (int p = 0; p < 2; ++p) {
            int col = (wv * 2 + p) * 16 + lcol;
            op[col] = ((h[p][r] - mu) * rin * gam[p] + bet[p]) * mk;
        }
    }
}

extern "C" void kernel_launch(void* const* d_in, const int* in_sizes, int n_in,
                              void* d_out, int out_size, void* d_ws, size_t ws_size,
                              hipStream_t stream)
{
    const float* x     = (const float*)d_in[0];
    const int*   ei    = (const int*)d_in[1];
    const float* nmask = (const float*)d_in[2];
    const float* em    = (const float*)d_in[3];
    const float* Wself = (const float*)d_in[4];
    const float* bself = (const float*)d_in[5];
    const float* Wnb   = (const float*)d_in[6];
    const float* bnb   = (const float*)d_in[7];
    const float* gamma = (const float*)d_in[8];
    const float* beta  = (const float*)d_in[9];
    float* out = (float*)d_out;

    // ws: cnt int[40000] | entries int2[40000*64] (20.48 MB) | Bt bf16[128*256]
    //     | xbf bf16[40000*128] (10.24 MB)   -> ~31 MB total
    int* cnt = (int*)d_ws;
    int2* entries = (int2*)(cnt + NNODES);                       // byte 160000, 8-al
    unsigned short* Bt = (unsigned short*)(entries + (size_t)NNODES * CAP);
    unsigned short* xbf = Bt + (size_t)128 * 256;                // 16-aligned

    hipMemsetAsync(cnt, 0, NNODES * sizeof(int), stream);
    fill_k<<<FILL_BLOCKS + CONV_BLOCKS + 128, 256, 0, stream>>>(
        ei, em, cnt, entries, x, xbf, Wself, Wnb, Bt);
    fused_k<<<8 * JB, 256, 0, stream>>>(xbf, cnt, entries, Bt,
                                        bself, bnb, gamma, beta, nmask, out);
}